// Round 2
// baseline (3306.331 us; speedup 1.0000x reference)
//
#include <hip/hip_runtime.h>
#include <hip/hip_bf16.h>

// Problem constants
#define BATCH 8
#define CDIM 192
#define HH 128
#define WW 128
#define HW (HH*WW)          // 16384
#define HEADS 4
#define CHD 48
#define NSL 16              // n-slices for attn kernel

// ---------------------------------------------------------------------------
// LayerNorm2d stats: per (b, pixel) mean / rstd over 192 channels
__global__ __launch_bounds__(256) void ln_stats_kernel(
    const float* __restrict__ x, float* __restrict__ mu, float* __restrict__ rstd)
{
    int idx = blockIdx.x * 256 + threadIdx.x;         // 0 .. B*HW-1
    int b = idx >> 14;                                 // /16384
    int p = idx & (HW - 1);
    const float* xp = x + (size_t)b * CDIM * HW + p;
    float s = 0.f, s2 = 0.f;
    for (int c = 0; c < CDIM; ++c) {
        float v = xp[(size_t)c * HW];
        s += v;
        s2 = fmaf(v, v, s2);
    }
    float m = s * (1.f / CDIM);
    float var = s2 * (1.f / CDIM) - m * m;
    mu[idx] = m;
    rstd[idx] = rsqrtf(var + 1e-6f);
}

// ---------------------------------------------------------------------------
// Row sum over HW for one (b,c) plane (used for SK pooling)
__global__ __launch_bounds__(256) void rowsum_kernel(
    const float* __restrict__ x, float* __restrict__ out)
{
    int row = blockIdx.x;                              // b*CDIM + c
    const float* xp = x + (size_t)row * HW;
    float s = 0.f;
    for (int i = threadIdx.x; i < HW; i += 256) s += xp[i];
    for (int msk = 32; msk; msk >>= 1) s += __shfl_xor(s, msk);
    __shared__ float sh[4];
    if ((threadIdx.x & 63) == 0) sh[threadIdx.x >> 6] = s;
    __syncthreads();
    if (threadIdx.x == 0) out[row] = sh[0] + sh[1] + sh[2] + sh[3];
}

// ---------------------------------------------------------------------------
// 1x1 conv with LayerNorm folded in.  grid (3 och-groups, HW/256, B), 256 thr.
// Each thread: 1 pixel, 64 output channels, K=192. Weight loads are wave-
// uniform -> compiler scalarizes to s_load.
__global__ __launch_bounds__(256, 2) void conv1x1_ln_kernel(
    const float* __restrict__ x, const float* __restrict__ mu, const float* __restrict__ rstd,
    const float* __restrict__ lnw, const float* __restrict__ lnb,
    const float* __restrict__ w, const float* __restrict__ wb,
    float* __restrict__ y)
{
    const int og = blockIdx.x;
    const int p  = blockIdx.y * 256 + threadIdx.x;
    const int b  = blockIdx.z;
    const size_t base = (size_t)b * CDIM * HW + p;
    const int sidx = (b << 14) + p;
    const float m = mu[sidx], r = rstd[sidx];
    float acc[64];
#pragma unroll
    for (int o = 0; o < 64; ++o) acc[o] = 0.f;
    const float* wr = w + og * 64 * CDIM;
    for (int c = 0; c < CDIM; ++c) {
        float xv = (x[base + (size_t)c * HW] - m) * r * lnw[c] + lnb[c];
#pragma unroll
        for (int o = 0; o < 64; ++o) acc[o] = fmaf(wr[o * CDIM + c], xv, acc[o]);
    }
    const size_t ybase = (size_t)b * CDIM * HW + (size_t)og * 64 * HW + p;
#pragma unroll
    for (int o = 0; o < 64; ++o) y[ybase + (size_t)o * HW] = acc[o] + wb[og * 64 + o];
}

// ---------------------------------------------------------------------------
// Plain 1x1 conv + bias + residual (proj stage)
__global__ __launch_bounds__(256, 2) void proj_kernel(
    const float* __restrict__ x, const float* __restrict__ w, const float* __restrict__ wb,
    const float* __restrict__ resid, float* __restrict__ y)
{
    const int og = blockIdx.x;
    const int p  = blockIdx.y * 256 + threadIdx.x;
    const int b  = blockIdx.z;
    const size_t base = (size_t)b * CDIM * HW + p;
    float acc[64];
#pragma unroll
    for (int o = 0; o < 64; ++o) acc[o] = 0.f;
    const float* wr = w + og * 64 * CDIM;
    for (int c = 0; c < CDIM; ++c) {
        float xv = x[base + (size_t)c * HW];
#pragma unroll
        for (int o = 0; o < 64; ++o) acc[o] = fmaf(wr[o * CDIM + c], xv, acc[o]);
    }
    const size_t ybase = (size_t)b * CDIM * HW + (size_t)og * 64 * HW + p;
#pragma unroll
    for (int o = 0; o < 64; ++o)
        y[ybase + (size_t)o * HW] = acc[o] + wb[og * 64 + o] + resid[ybase + (size_t)o * HW];
}

// ---------------------------------------------------------------------------
// Depthwise 3x3, SAME padding; optionally accumulates sum of squares of the
// output row (for L2 norm) via atomics.  grid (HW/256, CDIM, B)
__global__ __launch_bounds__(256) void dwconv_kernel(
    const float* __restrict__ x, const float* __restrict__ w, const float* __restrict__ bias,
    float* __restrict__ y, float* __restrict__ sumsq)
{
    const int tile = blockIdx.x;
    const int c = blockIdx.y;
    const int b = blockIdx.z;
    const int p = tile * 256 + threadIdx.x;
    const int i = p >> 7, j = p & 127;
    const float* xp = x + ((size_t)b * CDIM + c) * HW;
    float wv[9];
#pragma unroll
    for (int t = 0; t < 9; ++t) wv[t] = w[c * 9 + t];
    float acc = bias[c];
#pragma unroll
    for (int di = -1; di <= 1; ++di) {
        int ii = i + di;
        if (ii < 0 || ii >= HH) continue;
#pragma unroll
        for (int dj = -1; dj <= 1; ++dj) {
            int jj = j + dj;
            if (jj < 0 || jj >= WW) continue;
            acc = fmaf(wv[(di + 1) * 3 + (dj + 1)], xp[ii * WW + jj], acc);
        }
    }
    y[((size_t)b * CDIM + c) * HW + p] = acc;
    if (sumsq != nullptr) {
        float v2 = acc * acc;
        for (int msk = 32; msk; msk >>= 1) v2 += __shfl_xor(v2, msk);
        if ((threadIdx.x & 63) == 0) atomicAdd(&sumsq[b * CDIM + c], v2);
    }
}

// ---------------------------------------------------------------------------
// attn partial: per (b,h) 48x48 Gram matrix of q,k over an n-slice.
// grid (NSL, B*HEADS); 256 threads = 16x16 grid of 3x3 register tiles.
__global__ __launch_bounds__(256) void attn_kernel(
    const float* __restrict__ q, const float* __restrict__ k, float* __restrict__ attn)
{
    const int bh = blockIdx.y;
    const int b = bh >> 2, h = bh & 3;
    const int n0 = blockIdx.x * (HW / NSL);           // 1024-wide slice
    __shared__ float qs[48][65];
    __shared__ float ks[48][65];
    const int tid = threadIdx.x;
    const int c0 = (tid >> 4) * 3, d0 = (tid & 15) * 3;
    float s[3][3] = {{0.f,0.f,0.f},{0.f,0.f,0.f},{0.f,0.f,0.f}};
    const size_t qbase = ((size_t)b * CDIM + h * CHD) * HW;
    for (int ch = 0; ch < HW / NSL; ch += 64) {
        __syncthreads();
        for (int idx = tid; idx < 48 * 64; idx += 256) {
            int r = idx >> 6, col = idx & 63;
            qs[r][col] = q[qbase + (size_t)r * HW + n0 + ch + col];
            ks[r][col] = k[qbase + (size_t)r * HW + n0 + ch + col];
        }
        __syncthreads();
        for (int n = 0; n < 64; ++n) {
            float qv[3], kv[3];
#pragma unroll
            for (int t = 0; t < 3; ++t) { qv[t] = qs[c0 + t][n]; kv[t] = ks[d0 + t][n]; }
#pragma unroll
            for (int a = 0; a < 3; ++a)
#pragma unroll
                for (int e = 0; e < 3; ++e) s[a][e] = fmaf(qv[a], kv[e], s[a][e]);
        }
    }
    float* ap = attn + (size_t)bh * 48 * 48;
#pragma unroll
    for (int a = 0; a < 3; ++a)
#pragma unroll
        for (int e = 0; e < 3; ++e) atomicAdd(&ap[(c0 + a) * 48 + (d0 + e)], s[a][e]);
}

// ---------------------------------------------------------------------------
// Build P_eff = sum_i a_i * softmax(topk_mask_i(attn_scaled)).  One thread per
// attn row; per-thread column in LDS so dynamic indexing stays in LDS.
__global__ __launch_bounds__(64) void peff_kernel(
    const float* __restrict__ attn, const float* __restrict__ rq2, const float* __restrict__ rk2,
    const float* __restrict__ temp,
    const float* __restrict__ a1, const float* __restrict__ a2,
    const float* __restrict__ a3, const float* __restrict__ a4,
    float* __restrict__ peff)
{
    __shared__ float a_sh[48][64];
    __shared__ float e_sh[48][64];
    __shared__ float c_sh[48][64];
    const int t = threadIdx.x;
    const int r = blockIdx.x * 64 + t;                // 0..1535 (bh*48 + c)
    const int bh = r / 48, c = r - bh * 48;
    const int b = bh >> 2, h = bh & 3;
    const float T = temp[0];
    const float nq = sqrtf(rq2[b * CDIM + h * CHD + c]);
    const float scq = 1.f / fmaxf(nq, 1e-12f);
    float m = -1e30f;
    for (int d = 0; d < 48; ++d) {
        float nk = sqrtf(rk2[b * CDIM + h * CHD + d]);
        float a = attn[(size_t)r * 48 + d] * scq * (1.f / fmaxf(nk, 1e-12f)) * T;
        a_sh[d][t] = a;
        m = fmaxf(m, a);
    }
    float S1 = 0.f, S2 = 0.f, S3 = 0.f, S4 = 0.f;
    for (int d = 0; d < 48; ++d) {
        float ad = a_sh[d][t];
        int cnt = 0;
        for (int e = 0; e < 48; ++e) cnt += (a_sh[e][t] > ad) ? 1 : 0;
        float ed = expf(ad - m);
        e_sh[d][t] = ed;
        c_sh[d][t] = (float)cnt;
        if (cnt < 24) S1 += ed;
        if (cnt < 32) S2 += ed;
        if (cnt < 36) S3 += ed;
        if (cnt < 38) S4 += ed;
    }
    float w1 = a1[0] / S1, w2 = a2[0] / S2, w3 = a3[0] / S3, w4 = a4[0] / S4;
    for (int d = 0; d < 48; ++d) {
        float ed = e_sh[d][t];
        int cnt = (int)c_sh[d][t];
        float pw = 0.f;
        if (cnt < 24) pw += w1;
        if (cnt < 32) pw += w2;
        if (cnt < 36) pw += w3;
        if (cnt < 38) pw += w4;
        peff[(size_t)r * 48 + d] = ed * pw;
    }
}

// ---------------------------------------------------------------------------
// O = P_eff @ V.  grid (HW/256, HEADS, B); thread: 1 pixel, 48 out channels.
__global__ __launch_bounds__(256, 2) void pv_kernel(
    const float* __restrict__ peff, const float* __restrict__ v, float* __restrict__ o)
{
    const int p = blockIdx.x * 256 + threadIdx.x;
    const int h = blockIdx.y, b = blockIdx.z;
    const float* P = peff + (size_t)((b * HEADS + h) * 48) * 48;
    const size_t base = ((size_t)b * CDIM + h * CHD) * HW + p;
    float acc[48];
#pragma unroll
    for (int c = 0; c < 48; ++c) acc[c] = 0.f;
    for (int d = 0; d < 48; ++d) {
        float vv = v[base + (size_t)d * HW];
#pragma unroll
        for (int c = 0; c < 48; ++c) acc[c] = fmaf(P[c * 48 + d], vv, acc[c]);
    }
#pragma unroll
    for (int c = 0; c < 48; ++c) o[base + (size_t)c * HW] = acc[c];
}

// ---------------------------------------------------------------------------
// SK gate: pooled mean -> relu(W1 @ .) -> W2 @ . -> softmax over HEIGHT=2
__global__ __launch_bounds__(192) void gate_kernel(
    const float* __restrict__ sum_f1, const float* __restrict__ sum_td,
    const float* __restrict__ w1, const float* __restrict__ w2, float* __restrict__ gates)
{
    const int b = blockIdx.x;
    const int t = threadIdx.x;                        // 0..191
    __shared__ float pooled[192];
    __shared__ float z[24];
    pooled[t] = (sum_f1[b * CDIM + t] + sum_td[b * CDIM + t]) * (1.f / HW);
    __syncthreads();
    if (t < 24) {
        float s = 0.f;
        for (int c2 = 0; c2 < CDIM; ++c2) s += w1[t * CDIM + c2] * pooled[c2];
        z[t] = fmaxf(s, 0.f);
    }
    __syncthreads();
    float g0 = 0.f, g1 = 0.f;
    for (int j = 0; j < 24; ++j) {
        g0 += w2[t * 24 + j] * z[j];
        g1 += w2[(CDIM + t) * 24 + j] * z[j];
    }
    float mm = fmaxf(g0, g1);
    float e0 = expf(g0 - mm), e1 = expf(g1 - mm);
    float inv = 1.f / (e0 + e1);
    gates[b * CDIM + t] = e0 * inv;
    gates[BATCH * CDIM + b * CDIM + t] = e1 * inv;
}

// ---------------------------------------------------------------------------
// Final gating combine: out = f1*g0 + td*g1 (per-(b,c) gates), float4
__global__ __launch_bounds__(256) void final_kernel(
    const float* __restrict__ f1, const float* __restrict__ td,
    const float* __restrict__ gates, float* __restrict__ out)
{
    size_t i4 = (size_t)blockIdx.x * 256 + threadIdx.x;   // float4 index
    size_t i = i4 * 4;
    int plane = (int)(i / HW);                            // b*CDIM + c
    float g0 = gates[plane], g1 = gates[BATCH * CDIM + plane];
    float4 a = ((const float4*)f1)[i4];
    float4 d = ((const float4*)td)[i4];
    float4 r;
    r.x = a.x * g0 + d.x * g1;
    r.y = a.y * g0 + d.y * g1;
    r.z = a.z * g0 + d.z * g1;
    r.w = a.w * g0 + d.w * g1;
    ((float4*)out)[i4] = r;
}

// ---------------------------------------------------------------------------
extern "C" void kernel_launch(void* const* d_in, const int* in_sizes, int n_in,
                              void* d_out, int out_size, void* d_ws, size_t ws_size,
                              hipStream_t stream)
{
    const float* T_E  = (const float*)d_in[0];
    const float* C_E  = (const float*)d_in[1];
    const float* T_D  = (const float*)d_in[2];
    const float* tn_w = (const float*)d_in[3];
    const float* tn_b = (const float*)d_in[4];
    const float* cn_w = (const float*)d_in[5];
    const float* cn_b = (const float*)d_in[6];
    const float* q_w  = (const float*)d_in[7];
    const float* q_b  = (const float*)d_in[8];
    const float* q_dw = (const float*)d_in[9];
    const float* q_db = (const float*)d_in[10];
    const float* k_w  = (const float*)d_in[11];
    const float* k_b  = (const float*)d_in[12];
    const float* k_dw = (const float*)d_in[13];
    const float* k_db = (const float*)d_in[14];
    const float* v_w  = (const float*)d_in[15];
    const float* v_b  = (const float*)d_in[16];
    const float* v_dw = (const float*)d_in[17];
    const float* v_db = (const float*)d_in[18];
    const float* temp = (const float*)d_in[19];
    const float* p_w  = (const float*)d_in[20];
    const float* p_b  = (const float*)d_in[21];
    const float* a1   = (const float*)d_in[22];
    const float* a2   = (const float*)d_in[23];
    const float* a3   = (const float*)d_in[24];
    const float* a4   = (const float*)d_in[25];
    const float* skw1 = (const float*)d_in[26];
    const float* skw2 = (const float*)d_in[27];

    float* ws = (float*)d_ws;
    float* muT    = ws;                    // 131072
    float* rsT    = muT + 131072;
    float* muC    = rsT + 131072;
    float* rsC    = muC + 131072;
    float* rq2    = rsC + 131072;          // 1536
    float* rk2    = rq2 + 1536;
    float* sum_td = rk2 + 1536;
    float* sum_f1 = sum_td + 1536;
    float* attn   = sum_f1 + 1536;         // 73728
    float* peff   = attn + 73728;
    float* gates  = peff + 73728;          // 3072
    const size_t BIG = (size_t)BATCH * CDIM * HW;     // 25165824 floats
    float* bufA = ws + (1 << 20);
    float* bufB = bufA + BIG;
    float* bufC = bufB + BIG;
    float* outF = (float*)d_out;           // reused as q-buffer mid-pipeline

    // zero the small scratch region (atomics targets live here)
    hipMemsetAsync(ws, 0, (size_t)(1 << 20) * sizeof(float), stream);

    // LN stats + T_D pooled sums
    ln_stats_kernel<<<512, 256, 0, stream>>>(T_E, muT, rsT);
    ln_stats_kernel<<<512, 256, 0, stream>>>(C_E, muC, rsC);
    rowsum_kernel<<<BATCH * CDIM, 256, 0, stream>>>(T_D, sum_td);

    // 1x1 convs with LN folded
    dim3 cgrid(3, HW / 256, BATCH);
    conv1x1_ln_kernel<<<cgrid, 256, 0, stream>>>(T_E, muT, rsT, tn_w, tn_b, q_w, q_b, bufA);
    conv1x1_ln_kernel<<<cgrid, 256, 0, stream>>>(C_E, muC, rsC, cn_w, cn_b, k_w, k_b, bufB);
    conv1x1_ln_kernel<<<cgrid, 256, 0, stream>>>(C_E, muC, rsC, cn_w, cn_b, v_w, v_b, bufC);

    // depthwise 3x3 (+ sumsq for q,k)
    dim3 dgrid(HW / 256, CDIM, BATCH);
    dwconv_kernel<<<dgrid, 256, 0, stream>>>(bufA, q_dw, q_db, outF, rq2);   // q -> d_out
    dwconv_kernel<<<dgrid, 256, 0, stream>>>(bufB, k_dw, k_db, bufA, rk2);   // k -> bufA
    dwconv_kernel<<<dgrid, 256, 0, stream>>>(bufC, v_dw, v_db, bufB, nullptr); // v -> bufB

    // attention Gram matrix + P_eff
    attn_kernel<<<dim3(NSL, BATCH * HEADS), 256, 0, stream>>>(outF, bufA, attn);
    peff_kernel<<<24, 64, 0, stream>>>(attn, rq2, rk2, temp, a1, a2, a3, a4, peff);

    // O = P_eff @ V -> bufC
    pv_kernel<<<dim3(HW / 256, HEADS, BATCH), 256, 0, stream>>>(peff, bufB, bufC);

    // fusion1 = proj(O) + C_E -> bufA ; pooled sums
    proj_kernel<<<cgrid, 256, 0, stream>>>(bufC, p_w, p_b, C_E, bufA);
    rowsum_kernel<<<BATCH * CDIM, 256, 0, stream>>>(bufA, sum_f1);

    // SK gate + final combine
    gate_kernel<<<BATCH, 192, 0, stream>>>(sum_f1, sum_td, skw1, skw2, gates);
    final_kernel<<<(BIG / 4) / 256, 256, 0, stream>>>(bufA, T_D, gates, outF);
}

// Round 4
// 2258.671 us; speedup vs baseline: 1.4638x; 1.4638x over previous
//
#include <hip/hip_runtime.h>
#include <hip/hip_bf16.h>

// Problem constants
#define BATCH 8
#define CDIM 192
#define HH 128
#define WW 128
#define HW (HH*WW)          // 16384
#define HEADS 4
#define CHD 48
#define NSL 64              // n-slices for attn kernel (256 px each)

// ---------------------------------------------------------------------------
// LayerNorm2d stats, pass 1: partial sums over a 48-channel slice.
// grid (512, 4) x 256 thr.  8 waves/SIMD for latency hiding.
__global__ __launch_bounds__(256) void ln_part_kernel(
    const float* __restrict__ x, float* __restrict__ ps, float* __restrict__ ps2)
{
    const int idx = blockIdx.x * 256 + threadIdx.x;   // 0 .. B*HW-1
    const int slice = blockIdx.y;                      // 0..3
    const int b = idx >> 14;
    const int p = idx & (HW - 1);
    const float* xp = x + (size_t)b * CDIM * HW + (size_t)slice * 48 * HW + p;
    float s = 0.f, s2 = 0.f;
#pragma unroll 8
    for (int c = 0; c < 48; ++c) {
        float v = xp[(size_t)c * HW];
        s += v;
        s2 = fmaf(v, v, s2);
    }
    ps [slice * (BATCH * HW) + idx] = s;
    ps2[slice * (BATCH * HW) + idx] = s2;
}

// pass 2: combine 4 partials -> mu, rstd
__global__ __launch_bounds__(256) void ln_fin_kernel(
    const float* __restrict__ ps, const float* __restrict__ ps2,
    float* __restrict__ mu, float* __restrict__ rstd)
{
    const int idx = blockIdx.x * 256 + threadIdx.x;
    const int N = BATCH * HW;
    float s  = ps [idx] + ps [N + idx] + ps [2 * N + idx] + ps [3 * N + idx];
    float s2 = ps2[idx] + ps2[N + idx] + ps2[2 * N + idx] + ps2[3 * N + idx];
    float m = s * (1.f / CDIM);
    mu[idx] = m;
    rstd[idx] = rsqrtf(s2 * (1.f / CDIM) - m * m + 1e-6f);
}

// ---------------------------------------------------------------------------
// Row sum over HW for one (b,c) plane (SK pooling), float4
__global__ __launch_bounds__(256) void rowsum_kernel(
    const float* __restrict__ x, float* __restrict__ out)
{
    const int row = blockIdx.x;                        // b*CDIM + c
    const float4* xp = (const float4*)(x + (size_t)row * HW);
    float s = 0.f;
#pragma unroll
    for (int k = 0; k < 16; ++k) {
        float4 v = xp[threadIdx.x + k * 256];
        s += (v.x + v.y) + (v.z + v.w);
    }
    for (int msk = 32; msk; msk >>= 1) s += __shfl_xor(s, msk);
    __shared__ float sh[4];
    if ((threadIdx.x & 63) == 0) sh[threadIdx.x >> 6] = s;
    __syncthreads();
    if (threadIdx.x == 0) out[row] = sh[0] + sh[1] + sh[2] + sh[3];
}

// ---------------------------------------------------------------------------
// 1x1 conv with LayerNorm folded in.  grid (3 och-groups, HW/256, B), 256 thr.
__global__ __launch_bounds__(256, 2) void conv1x1_ln_kernel(
    const float* __restrict__ x, const float* __restrict__ mu, const float* __restrict__ rstd,
    const float* __restrict__ lnw, const float* __restrict__ lnb,
    const float* __restrict__ w, const float* __restrict__ wb,
    float* __restrict__ y)
{
    const int og = blockIdx.x;
    const int p  = blockIdx.y * 256 + threadIdx.x;
    const int b  = blockIdx.z;
    const size_t base = (size_t)b * CDIM * HW + p;
    const int sidx = (b << 14) + p;
    const float m = mu[sidx], r = rstd[sidx];
    float acc[64];
#pragma unroll
    for (int o = 0; o < 64; ++o) acc[o] = 0.f;
    const float* wr = w + og * 64 * CDIM;
    for (int c = 0; c < CDIM; ++c) {
        float xv = (x[base + (size_t)c * HW] - m) * r * lnw[c] + lnb[c];
#pragma unroll
        for (int o = 0; o < 64; ++o) acc[o] = fmaf(wr[o * CDIM + c], xv, acc[o]);
    }
    const size_t ybase = (size_t)b * CDIM * HW + (size_t)og * 64 * HW + p;
#pragma unroll
    for (int o = 0; o < 64; ++o) y[ybase + (size_t)o * HW] = acc[o] + wb[og * 64 + o];
}

// ---------------------------------------------------------------------------
// Depthwise 3x3, SAME.  Thread = 16 contiguous px in one row; 18 float4 loads
// (3 rows x 6), register-shift stencil, 4 float4 stores.
// grid (HH/32, CDIM, BATCH) x 256 thr (8 col-chunks x 32 rows).
__global__ __launch_bounds__(256) void dwconv_kernel(
    const float* __restrict__ x, const float* __restrict__ w, const float* __restrict__ bias,
    float* __restrict__ y, float* __restrict__ sumsq)
{
    const int rt = blockIdx.x, c = blockIdx.y, b = blockIdx.z;
    const int tid = threadIdx.x;
    const int lrow = tid >> 3;                 // 0..31
    const int c16  = (tid & 7) * 16;           // 0,16,..,112
    const int gr = rt * 32 + lrow;             // global row
    const float* xp = x + ((size_t)b * CDIM + c) * HW;

    float wv[9];
#pragma unroll
    for (int t = 0; t < 9; ++t) wv[t] = w[c * 9 + t];
    const float bs = bias[c];

    float rb[3][24];
#pragma unroll
    for (int dr = 0; dr < 3; ++dr) {
        const int grr = gr + dr - 1;
        const bool ok = (grr >= 0) && (grr < HH);
        const float4* rp = (const float4*)(xp + (size_t)(ok ? grr : 0) * WW);
        float4 z = make_float4(0.f, 0.f, 0.f, 0.f);
        float4 t0 = (ok && c16 > 0)        ? rp[(c16 >> 2) - 1] : z;
        float4 t1 = ok ? rp[(c16 >> 2) + 0] : z;
        float4 t2 = ok ? rp[(c16 >> 2) + 1] : z;
        float4 t3 = ok ? rp[(c16 >> 2) + 2] : z;
        float4 t4 = ok ? rp[(c16 >> 2) + 3] : z;
        float4 t5 = (ok && c16 + 16 < WW)  ? rp[(c16 >> 2) + 4] : z;
        *(float4*)&rb[dr][0]  = t0;
        *(float4*)&rb[dr][4]  = t1;
        *(float4*)&rb[dr][8]  = t2;
        *(float4*)&rb[dr][12] = t3;
        *(float4*)&rb[dr][16] = t4;
        *(float4*)&rb[dr][20] = t5;
    }

    float out[16];
#pragma unroll
    for (int p = 0; p < 16; ++p) out[p] = bs;
#pragma unroll
    for (int dr = 0; dr < 3; ++dr) {
#pragma unroll
        for (int p = 0; p < 16; ++p) {
            out[p] = fmaf(wv[dr * 3 + 0], rb[dr][3 + p], out[p]);
            out[p] = fmaf(wv[dr * 3 + 1], rb[dr][4 + p], out[p]);
            out[p] = fmaf(wv[dr * 3 + 2], rb[dr][5 + p], out[p]);
        }
    }

    float* yp = y + ((size_t)b * CDIM + c) * HW + (size_t)gr * WW + c16;
#pragma unroll
    for (int q = 0; q < 4; ++q)
        ((float4*)yp)[q] = make_float4(out[4*q], out[4*q+1], out[4*q+2], out[4*q+3]);

    if (sumsq != nullptr) {
        float ss = 0.f;
#pragma unroll
        for (int p = 0; p < 16; ++p) ss = fmaf(out[p], out[p], ss);
        for (int msk = 32; msk; msk >>= 1) ss += __shfl_xor(ss, msk);
        __shared__ float sh[4];
        if ((tid & 63) == 0) sh[tid >> 6] = ss;
        __syncthreads();
        if (tid == 0) atomicAdd(&sumsq[b * CDIM + c], sh[0] + sh[1] + sh[2] + sh[3]);
    }
}

// ---------------------------------------------------------------------------
// attn partial: per (b,h) 48x48 Gram matrix of q,k over a 256-px slice.
// grid (NSL, B*HEADS); 256 threads = 16x16 grid of 3x3 register tiles.
__global__ __launch_bounds__(256) void attn_kernel(
    const float* __restrict__ q, const float* __restrict__ k, float* __restrict__ attn)
{
    const int bh = blockIdx.y;
    const int b = bh >> 2, h = bh & 3;
    const int n0 = blockIdx.x * (HW / NSL);           // 256-wide slice
    __shared__ float qs[48][65];
    __shared__ float ks[48][65];
    const int tid = threadIdx.x;
    const int c0 = (tid >> 4) * 3, d0 = (tid & 15) * 3;
    float s[3][3] = {{0.f,0.f,0.f},{0.f,0.f,0.f},{0.f,0.f,0.f}};
    const size_t qbase = ((size_t)b * CDIM + h * CHD) * HW;
    for (int ch = 0; ch < HW / NSL; ch += 64) {
        __syncthreads();
        for (int idx = tid; idx < 48 * 64; idx += 256) {
            int r = idx >> 6, col = idx & 63;
            qs[r][col] = q[qbase + (size_t)r * HW + n0 + ch + col];
            ks[r][col] = k[qbase + (size_t)r * HW + n0 + ch + col];
        }
        __syncthreads();
        for (int n = 0; n < 64; ++n) {
            float qv[3], kv[3];
#pragma unroll
            for (int t = 0; t < 3; ++t) { qv[t] = qs[c0 + t][n]; kv[t] = ks[d0 + t][n]; }
#pragma unroll
            for (int a = 0; a < 3; ++a)
#pragma unroll
                for (int e = 0; e < 3; ++e) s[a][e] = fmaf(qv[a], kv[e], s[a][e]);
        }
    }
    float* ap = attn + (size_t)bh * 48 * 48;
#pragma unroll
    for (int a = 0; a < 3; ++a)
#pragma unroll
        for (int e = 0; e < 3; ++e) atomicAdd(&ap[(c0 + a) * 48 + (d0 + e)], s[a][e]);
}

// ---------------------------------------------------------------------------
// Build P_eff = sum_i a_i * softmax(topk_mask_i(attn_scaled)).
__global__ __launch_bounds__(64) void peff_kernel(
    const float* __restrict__ attn, const float* __restrict__ rq2, const float* __restrict__ rk2,
    const float* __restrict__ temp,
    const float* __restrict__ a1, const float* __restrict__ a2,
    const float* __restrict__ a3, const float* __restrict__ a4,
    float* __restrict__ peff)
{
    __shared__ float a_sh[48][64];
    __shared__ float e_sh[48][64];
    __shared__ float c_sh[48][64];
    const int t = threadIdx.x;
    const int r = blockIdx.x * 64 + t;                // 0..1535 (bh*48 + c)
    const int bh = r / 48, c = r - bh * 48;
    const int b = bh >> 2, h = bh & 3;
    const float T = temp[0];
    const float nq = sqrtf(rq2[b * CDIM + h * CHD + c]);
    const float scq = 1.f / fmaxf(nq, 1e-12f);
    float m = -1e30f;
    for (int d = 0; d < 48; ++d) {
        float nk = sqrtf(rk2[b * CDIM + h * CHD + d]);
        float a = attn[(size_t)r * 48 + d] * scq * (1.f / fmaxf(nk, 1e-12f)) * T;
        a_sh[d][t] = a;
        m = fmaxf(m, a);
    }
    float S1 = 0.f, S2 = 0.f, S3 = 0.f, S4 = 0.f;
    for (int d = 0; d < 48; ++d) {
        float ad = a_sh[d][t];
        int cnt = 0;
        for (int e = 0; e < 48; ++e) cnt += (a_sh[e][t] > ad) ? 1 : 0;
        float ed = expf(ad - m);
        e_sh[d][t] = ed;
        c_sh[d][t] = (float)cnt;
        if (cnt < 24) S1 += ed;
        if (cnt < 32) S2 += ed;
        if (cnt < 36) S3 += ed;
        if (cnt < 38) S4 += ed;
    }
    float w1 = a1[0] / S1, w2 = a2[0] / S2, w3 = a3[0] / S3, w4 = a4[0] / S4;
    for (int d = 0; d < 48; ++d) {
        float ed = e_sh[d][t];
        int cnt = (int)c_sh[d][t];
        float pw = 0.f;
        if (cnt < 24) pw += w1;
        if (cnt < 32) pw += w2;
        if (cnt < 36) pw += w3;
        if (cnt < 38) pw += w4;
        peff[(size_t)r * 48 + d] = ed * pw;
    }
}

// ---------------------------------------------------------------------------
// M[b] = proj_w @ blockdiag(P_eff[b,h]) : grid (B, HEADS), 192 threads.
// M[b][o][h*48+d] = sum_c proj_w[o][h*48+c] * peff[b,h][c][d]
__global__ __launch_bounds__(192) void mmat_kernel(
    const float* __restrict__ peff, const float* __restrict__ pw, float* __restrict__ M)
{
    const int b = blockIdx.x, h = blockIdx.y, o = threadIdx.x;
    __shared__ float pf[48 * 48];
    for (int i = o; i < 48 * 48; i += 192) pf[i] = peff[(size_t)(b * HEADS + h) * 2304 + i];
    __syncthreads();
    float pwr[48];
#pragma unroll
    for (int cc = 0; cc < 48; ++cc) pwr[cc] = pw[o * CDIM + h * CHD + cc];
    float* Mo = M + ((size_t)b * CDIM + o) * CDIM + h * CHD;
    for (int d = 0; d < 48; ++d) {
        float s = 0.f;
#pragma unroll
        for (int cc = 0; cc < 48; ++cc) s = fmaf(pwr[cc], pf[cc * 48 + d], s);
        Mo[d] = s;
    }
}

// ---------------------------------------------------------------------------
// fusion1 = M[b] @ v + proj_b + C_E, with per-channel rowsum fused (atomic).
// grid (3 og, HW/256, B), 256 thr.
__global__ __launch_bounds__(256, 2) void projfuse_kernel(
    const float* __restrict__ v, const float* __restrict__ M, const float* __restrict__ pb,
    const float* __restrict__ resid, float* __restrict__ y, float* __restrict__ sum_f1)
{
    const int og = blockIdx.x;
    const int p  = blockIdx.y * 256 + threadIdx.x;
    const int b  = blockIdx.z;
    const size_t base = (size_t)b * CDIM * HW + p;
    const float* Mr = M + (size_t)b * CDIM * CDIM + og * 64 * CDIM;
    float acc[64];
#pragma unroll
    for (int o = 0; o < 64; ++o) acc[o] = 0.f;
    for (int c = 0; c < CDIM; ++c) {
        float xv = v[base + (size_t)c * HW];
#pragma unroll
        for (int o = 0; o < 64; ++o) acc[o] = fmaf(Mr[o * CDIM + c], xv, acc[o]);
    }
    const size_t ybase = (size_t)b * CDIM * HW + (size_t)og * 64 * HW + p;
    const int lane = threadIdx.x & 63, wv_ = threadIdx.x >> 6;
    __shared__ float s_sh[4][64];
    float myo = 0.f;
#pragma unroll
    for (int o = 0; o < 64; ++o) {
        float val = acc[o] + pb[og * 64 + o] + resid[ybase + (size_t)o * HW];
        y[ybase + (size_t)o * HW] = val;
        for (int msk = 32; msk; msk >>= 1) val += __shfl_xor(val, msk);
        if (lane == o) myo = val;
    }
    s_sh[wv_][lane] = myo;
    __syncthreads();
    if (threadIdx.x < 64) {
        float tsum = s_sh[0][threadIdx.x] + s_sh[1][threadIdx.x]
                   + s_sh[2][threadIdx.x] + s_sh[3][threadIdx.x];
        atomicAdd(&sum_f1[b * CDIM + og * 64 + threadIdx.x], tsum);
    }
}

// ---------------------------------------------------------------------------
// SK gate: pooled mean -> relu(W1 @ .) -> W2 @ . -> softmax over HEIGHT=2
__global__ __launch_bounds__(192) void gate_kernel(
    const float* __restrict__ sum_f1, const float* __restrict__ sum_td,
    const float* __restrict__ w1, const float* __restrict__ w2, float* __restrict__ gates)
{
    const int b = blockIdx.x;
    const int t = threadIdx.x;                        // 0..191
    __shared__ float pooled[192];
    __shared__ float z[24];
    pooled[t] = (sum_f1[b * CDIM + t] + sum_td[b * CDIM + t]) * (1.f / HW);
    __syncthreads();
    if (t < 24) {
        float s = 0.f;
        for (int c2 = 0; c2 < CDIM; ++c2) s += w1[t * CDIM + c2] * pooled[c2];
        z[t] = fmaxf(s, 0.f);
    }
    __syncthreads();
    float g0 = 0.f, g1 = 0.f;
    for (int j = 0; j < 24; ++j) {
        g0 += w2[t * 24 + j] * z[j];
        g1 += w2[(CDIM + t) * 24 + j] * z[j];
    }
    float mm = fmaxf(g0, g1);
    float e0 = expf(g0 - mm), e1 = expf(g1 - mm);
    float inv = 1.f / (e0 + e1);
    gates[b * CDIM + t] = e0 * inv;
    gates[BATCH * CDIM + b * CDIM + t] = e1 * inv;
}

// ---------------------------------------------------------------------------
// Final gating combine: out = f1*g0 + td*g1 (per-(b,c) gates), float4
__global__ __launch_bounds__(256) void final_kernel(
    const float* __restrict__ f1, const float* __restrict__ td,
    const float* __restrict__ gates, float* __restrict__ out)
{
    size_t i4 = (size_t)blockIdx.x * 256 + threadIdx.x;   // float4 index
    size_t i = i4 * 4;
    int plane = (int)(i / HW);                            // b*CDIM + c
    float g0 = gates[plane], g1 = gates[BATCH * CDIM + plane];
    float4 a = ((const float4*)f1)[i4];
    float4 d = ((const float4*)td)[i4];
    float4 r;
    r.x = a.x * g0 + d.x * g1;
    r.y = a.y * g0 + d.y * g1;
    r.z = a.z * g0 + d.z * g1;
    r.w = a.w * g0 + d.w * g1;
    ((float4*)out)[i4] = r;
}

// ---------------------------------------------------------------------------
extern "C" void kernel_launch(void* const* d_in, const int* in_sizes, int n_in,
                              void* d_out, int out_size, void* d_ws, size_t ws_size,
                              hipStream_t stream)
{
    const float* T_E  = (const float*)d_in[0];
    const float* C_E  = (const float*)d_in[1];
    const float* T_D  = (const float*)d_in[2];
    const float* tn_w = (const float*)d_in[3];
    const float* tn_b = (const float*)d_in[4];
    const float* cn_w = (const float*)d_in[5];
    const float* cn_b = (const float*)d_in[6];
    const float* q_w  = (const float*)d_in[7];
    const float* q_b  = (const float*)d_in[8];
    const float* q_dw = (const float*)d_in[9];
    const float* q_db = (const float*)d_in[10];
    const float* k_w  = (const float*)d_in[11];
    const float* k_b  = (const float*)d_in[12];
    const float* k_dw = (const float*)d_in[13];
    const float* k_db = (const float*)d_in[14];
    const float* v_w  = (const float*)d_in[15];
    const float* v_b  = (const float*)d_in[16];
    const float* v_dw = (const float*)d_in[17];
    const float* v_db = (const float*)d_in[18];
    const float* temp = (const float*)d_in[19];
    const float* p_w  = (const float*)d_in[20];
    const float* p_b  = (const float*)d_in[21];
    const float* a1   = (const float*)d_in[22];
    const float* a2   = (const float*)d_in[23];
    const float* a3   = (const float*)d_in[24];
    const float* a4   = (const float*)d_in[25];
    const float* skw1 = (const float*)d_in[26];
    const float* skw2 = (const float*)d_in[27];

    float* ws = (float*)d_ws;
    // small region (atomics targets first -> covered by one memset)
    float* rq2    = ws;                    // 1536
    float* rk2    = rq2 + 1536;            // 1536
    float* sum_td = rk2 + 1536;            // 1536 (direct store)
    float* sum_f1 = sum_td + 1536;         // 1536 (atomic)
    float* attn   = sum_f1 + 1536;         // 73728 (atomic)  -> memset ends at 79872
    float* peff   = attn + 73728;          // 73728
    float* gates  = peff + 73728;          // 3072
    float* Mmat   = gates + 3072;          // 294912
    float* muT    = Mmat + 294912;         // 131072
    float* rsT    = muT + 131072;
    float* muC    = rsT + 131072;
    float* rsC    = muC + 131072;          // ends < 1M floats

    const size_t BIG = (size_t)BATCH * CDIM * HW;     // 25165824 floats
    float* bufA = ws + (1 << 20);
    float* bufB = bufA + BIG;
    float* bufC = bufB + BIG;
    // ln partial sums live in bufC's region (bufC first written later by conv-v)
    float* lps  = bufC;                    // 524288
    float* lps2 = bufC + 524288;           // 524288
    float* outF = (float*)d_out;           // reused as q-buffer mid-pipeline

    // zero the atomic targets
    hipMemsetAsync(ws, 0, (size_t)79872 * sizeof(float), stream);

    // LayerNorm stats (two-pass) + T_D pooled sums
    dim3 lgrid(512, 4);
    ln_part_kernel<<<lgrid, 256, 0, stream>>>(T_E, lps, lps2);
    ln_fin_kernel<<<512, 256, 0, stream>>>(lps, lps2, muT, rsT);
    ln_part_kernel<<<lgrid, 256, 0, stream>>>(C_E, lps, lps2);
    ln_fin_kernel<<<512, 256, 0, stream>>>(lps, lps2, muC, rsC);
    rowsum_kernel<<<BATCH * CDIM, 256, 0, stream>>>(T_D, sum_td);

    // 1x1 convs with LN folded
    dim3 cgrid(3, HW / 256, BATCH);
    conv1x1_ln_kernel<<<cgrid, 256, 0, stream>>>(T_E, muT, rsT, tn_w, tn_b, q_w, q_b, bufA);
    conv1x1_ln_kernel<<<cgrid, 256, 0, stream>>>(C_E, muC, rsC, cn_w, cn_b, k_w, k_b, bufB);
    conv1x1_ln_kernel<<<cgrid, 256, 0, stream>>>(C_E, muC, rsC, cn_w, cn_b, v_w, v_b, bufC);

    // depthwise 3x3 (+ sumsq for q,k)
    dim3 dgrid(HH / 32, CDIM, BATCH);
    dwconv_kernel<<<dgrid, 256, 0, stream>>>(bufA, q_dw, q_db, outF, rq2);     // q -> d_out
    dwconv_kernel<<<dgrid, 256, 0, stream>>>(bufB, k_dw, k_db, bufA, rk2);     // k -> bufA
    dwconv_kernel<<<dgrid, 256, 0, stream>>>(bufC, v_dw, v_db, bufB, nullptr); // v -> bufB

    // attention Gram matrix + P_eff + fused proj matrix
    attn_kernel<<<dim3(NSL, BATCH * HEADS), 256, 0, stream>>>(outF, bufA, attn);
    peff_kernel<<<24, 64, 0, stream>>>(attn, rq2, rk2, temp, a1, a2, a3, a4, peff);
    mmat_kernel<<<dim3(BATCH, HEADS), 192, 0, stream>>>(peff, p_w, Mmat);

    // fusion1 = M @ v + p_b + C_E -> bufC ; rowsum fused
    projfuse_kernel<<<cgrid, 256, 0, stream>>>(bufB, Mmat, p_b, C_E, bufC, sum_f1);

    // SK gate + final combine
    gate_kernel<<<BATCH, 192, 0, stream>>>(sum_f1, sum_td, skw1, skw2, gates);
    final_kernel<<<(BIG / 4) / 256, 256, 0, stream>>>(bufC, T_D, gates, outF);
}

// Round 9
// 1164.176 us; speedup vs baseline: 2.8401x; 1.9401x over previous
//
#include <hip/hip_runtime.h>
#include <hip/hip_bf16.h>

// Problem constants
#define BATCH 8
#define CDIM 192
#define HH 128
#define WW 128
#define HW (HH*WW)          // 16384
#define HEADS 4
#define CHD 48
#define NSL 64              // n-slices for attn kernel (256 px each)
#define LDK 40              // padded LDS k-stride (bf16 units)

typedef __attribute__((ext_vector_type(8))) short bf16x8;
typedef __attribute__((ext_vector_type(4))) float f32x4;

__device__ inline unsigned short f2bf(float f) {
    union { float f; unsigned int u; } v; v.f = f;
    unsigned int u = v.u;
    unsigned int r = u + 0x7fff + ((u >> 16) & 1);   // RNE
    return (unsigned short)(r >> 16);
}

// ---------------------------------------------------------------------------
// LayerNorm2d stats, pass 1: partial sums over a 48-channel slice.
__global__ __launch_bounds__(256) void ln_part_kernel(
    const float* __restrict__ x, float* __restrict__ ps, float* __restrict__ ps2)
{
    const int idx = blockIdx.x * 256 + threadIdx.x;   // 0 .. B*HW-1
    const int slice = blockIdx.y;                      // 0..3
    const int b = idx >> 14;
    const int p = idx & (HW - 1);
    const float* xp = x + (size_t)b * CDIM * HW + (size_t)slice * 48 * HW + p;
    float s = 0.f, s2 = 0.f;
#pragma unroll 8
    for (int c = 0; c < 48; ++c) {
        float v = xp[(size_t)c * HW];
        s += v;
        s2 = fmaf(v, v, s2);
    }
    ps [slice * (BATCH * HW) + idx] = s;
    ps2[slice * (BATCH * HW) + idx] = s2;
}

// pass 2: combine 4 partials -> mu, rstd
__global__ __launch_bounds__(256) void ln_fin_kernel(
    const float* __restrict__ ps, const float* __restrict__ ps2,
    float* __restrict__ mu, float* __restrict__ rstd)
{
    const int idx = blockIdx.x * 256 + threadIdx.x;
    const int N = BATCH * HW;
    float s  = ps [idx] + ps [N + idx] + ps [2 * N + idx] + ps [3 * N + idx];
    float s2 = ps2[idx] + ps2[N + idx] + ps2[2 * N + idx] + ps2[3 * N + idx];
    float m = s * (1.f / CDIM);
    mu[idx] = m;
    rstd[idx] = rsqrtf(s2 * (1.f / CDIM) - m * m + 1e-6f);
}

// ---------------------------------------------------------------------------
// Row sum over HW for one (b,c) plane (SK pooling), float4
__global__ __launch_bounds__(256) void rowsum_kernel(
    const float* __restrict__ x, float* __restrict__ out)
{
    const int row = blockIdx.x;                        // b*CDIM + c
    const float4* xp = (const float4*)(x + (size_t)row * HW);
    float s = 0.f;
#pragma unroll
    for (int k = 0; k < 16; ++k) {
        float4 v = xp[threadIdx.x + k * 256];
        s += (v.x + v.y) + (v.z + v.w);
    }
    for (int msk = 32; msk; msk >>= 1) s += __shfl_xor(s, msk);
    __shared__ float sh[4];
    if ((threadIdx.x & 63) == 0) sh[threadIdx.x >> 6] = s;
    __syncthreads();
    if (threadIdx.x == 0) out[row] = sh[0] + sh[1] + sh[2] + sh[3];
}

// ---------------------------------------------------------------------------
// MFMA 1x1 conv with LayerNorm folded: Y[192,64px] = W[192,192] @ LN(X)[192,64px]
// grid (HW/64, B) x 256 thr (4 waves, wave w covers cols w*16..w*16+15).
__global__ __launch_bounds__(256) void conv1x1_mfma_ln(
    const float* __restrict__ x, const float* __restrict__ mu, const float* __restrict__ rstd,
    const float* __restrict__ lnw, const float* __restrict__ lnb,
    const float* __restrict__ w, const float* __restrict__ wb,
    float* __restrict__ y)
{
    __shared__ short A_s[CDIM * LDK];
    __shared__ short B_s[64 * LDK];
    const int tid = threadIdx.x;
    const int p0 = blockIdx.x * 64;
    const int b  = blockIdx.y;
    const int lane = tid & 63;
    const int wid = tid >> 6;            // 0..3 (n-slot AND staging k-group)
    const int p_l = tid & 63;            // staging pixel / A staging row base

    const int sidx = (b << 14) + p0 + p_l;
    const float m_ln = mu[sidx], r_ln = rstd[sidx];

    f32x4 acc[12];
#pragma unroll
    for (int i = 0; i < 12; ++i) acc[i] = f32x4{0.f, 0.f, 0.f, 0.f};

    const size_t xb = (size_t)b * CDIM * HW + p0;

    for (int ks = 0; ks < 6; ++ks) {
        const int k0 = ks * 32;
        if (ks) __syncthreads();
        // stage A: 192 rows x 32 k of W, fp32 -> bf16
#pragma unroll
        for (int j = 0; j < 3; ++j) {
            const int row = p_l + 64 * j;
#pragma unroll
            for (int i = 0; i < 2; ++i) {
                const int c = k0 + wid * 8 + i * 4;
                const float4 wv = *(const float4*)(w + (size_t)row * CDIM + c);
                unsigned int lo = f2bf(wv.x) | ((unsigned int)f2bf(wv.y) << 16);
                unsigned int hi = f2bf(wv.z) | ((unsigned int)f2bf(wv.w) << 16);
                *(uint2*)&A_s[row * LDK + wid * 8 + i * 4] = make_uint2(lo, hi);
            }
        }
        // stage B: 64 px x 32 k of LN(x), fp32 -> bf16
#pragma unroll
        for (int i = 0; i < 2; ++i) {
            const int c = k0 + wid * 8 + i * 4;
            float v0 = x[xb + (size_t)(c + 0) * HW + p_l];
            float v1 = x[xb + (size_t)(c + 1) * HW + p_l];
            float v2 = x[xb + (size_t)(c + 2) * HW + p_l];
            float v3 = x[xb + (size_t)(c + 3) * HW + p_l];
            v0 = (v0 - m_ln) * r_ln * lnw[c + 0] + lnb[c + 0];
            v1 = (v1 - m_ln) * r_ln * lnw[c + 1] + lnb[c + 1];
            v2 = (v2 - m_ln) * r_ln * lnw[c + 2] + lnb[c + 2];
            v3 = (v3 - m_ln) * r_ln * lnw[c + 3] + lnb[c + 3];
            unsigned int lo = f2bf(v0) | ((unsigned int)f2bf(v1) << 16);
            unsigned int hi = f2bf(v2) | ((unsigned int)f2bf(v3) << 16);
            *(uint2*)&B_s[p_l * LDK + wid * 8 + i * 4] = make_uint2(lo, hi);
        }
        __syncthreads();
        // compute: 12 m-frags x 1 n-frag per wave
        const bf16x8 bfr = *(const bf16x8*)&B_s[(wid * 16 + (lane & 15)) * LDK + (lane >> 4) * 8];
#pragma unroll
        for (int mi = 0; mi < 12; ++mi) {
            const bf16x8 afr = *(const bf16x8*)&A_s[(mi * 16 + (lane & 15)) * LDK + (lane >> 4) * 8];
            acc[mi] = __builtin_amdgcn_mfma_f32_16x16x32_bf16(afr, bfr, acc[mi], 0, 0, 0);
        }
    }
    const int col = p0 + wid * 16 + (lane & 15);
#pragma unroll
    for (int mi = 0; mi < 12; ++mi) {
#pragma unroll
        for (int r = 0; r < 4; ++r) {
            const int row = mi * 16 + (lane >> 4) * 4 + r;
            y[((size_t)b * CDIM + row) * HW + col] = acc[mi][r] + wb[row];
        }
    }
}

// ---------------------------------------------------------------------------
// MFMA fused proj: Y = M[b] @ V + pb + C_E.  Same structure, no LN.
__global__ __launch_bounds__(256) void projfuse_mfma(
    const float* __restrict__ v, const float* __restrict__ M,
    const float* __restrict__ pb, const float* __restrict__ resid,
    float* __restrict__ y)
{
    __shared__ short A_s[CDIM * LDK];
    __shared__ short B_s[64 * LDK];
    const int tid = threadIdx.x;
    const int p0 = blockIdx.x * 64;
    const int b  = blockIdx.y;
    const int lane = tid & 63;
    const int wid = tid >> 6;
    const int p_l = tid & 63;

    f32x4 acc[12];
#pragma unroll
    for (int i = 0; i < 12; ++i) acc[i] = f32x4{0.f, 0.f, 0.f, 0.f};

    const size_t xb = (size_t)b * CDIM * HW + p0;
    const float* Mb = M + (size_t)b * CDIM * CDIM;

    for (int ks = 0; ks < 6; ++ks) {
        const int k0 = ks * 32;
        if (ks) __syncthreads();
#pragma unroll
        for (int j = 0; j < 3; ++j) {
            const int row = p_l + 64 * j;
#pragma unroll
            for (int i = 0; i < 2; ++i) {
                const int c = k0 + wid * 8 + i * 4;
                const float4 wv = *(const float4*)(Mb + (size_t)row * CDIM + c);
                unsigned int lo = f2bf(wv.x) | ((unsigned int)f2bf(wv.y) << 16);
                unsigned int hi = f2bf(wv.z) | ((unsigned int)f2bf(wv.w) << 16);
                *(uint2*)&A_s[row * LDK + wid * 8 + i * 4] = make_uint2(lo, hi);
            }
        }
#pragma unroll
        for (int i = 0; i < 2; ++i) {
            const int c = k0 + wid * 8 + i * 4;
            float v0 = v[xb + (size_t)(c + 0) * HW + p_l];
            float v1 = v[xb + (size_t)(c + 1) * HW + p_l];
            float v2 = v[xb + (size_t)(c + 2) * HW + p_l];
            float v3 = v[xb + (size_t)(c + 3) * HW + p_l];
            unsigned int lo = f2bf(v0) | ((unsigned int)f2bf(v1) << 16);
            unsigned int hi = f2bf(v2) | ((unsigned int)f2bf(v3) << 16);
            *(uint2*)&B_s[p_l * LDK + wid * 8 + i * 4] = make_uint2(lo, hi);
        }
        __syncthreads();
        const bf16x8 bfr = *(const bf16x8*)&B_s[(wid * 16 + (lane & 15)) * LDK + (lane >> 4) * 8];
#pragma unroll
        for (int mi = 0; mi < 12; ++mi) {
            const bf16x8 afr = *(const bf16x8*)&A_s[(mi * 16 + (lane & 15)) * LDK + (lane >> 4) * 8];
            acc[mi] = __builtin_amdgcn_mfma_f32_16x16x32_bf16(afr, bfr, acc[mi], 0, 0, 0);
        }
    }
    const int col = p0 + wid * 16 + (lane & 15);
#pragma unroll
    for (int mi = 0; mi < 12; ++mi) {
#pragma unroll
        for (int r = 0; r < 4; ++r) {
            const int row = mi * 16 + (lane >> 4) * 4 + r;
            const size_t o = ((size_t)b * CDIM + row) * HW + col;
            y[o] = acc[mi][r] + pb[row] + resid[o];
        }
    }
}

// ---------------------------------------------------------------------------
// Depthwise 3x3, SAME.  Thread = 16 contiguous px in one row.
__global__ __launch_bounds__(256) void dwconv_kernel(
    const float* __restrict__ x, const float* __restrict__ w, const float* __restrict__ bias,
    float* __restrict__ y, float* __restrict__ sumsq)
{
    const int rt = blockIdx.x, c = blockIdx.y, b = blockIdx.z;
    const int tid = threadIdx.x;
    const int lrow = tid >> 3;                 // 0..31
    const int c16  = (tid & 7) * 16;           // 0,16,..,112
    const int gr = rt * 32 + lrow;             // global row
    const float* xp = x + ((size_t)b * CDIM + c) * HW;

    float wv[9];
#pragma unroll
    for (int t = 0; t < 9; ++t) wv[t] = w[c * 9 + t];
    const float bs = bias[c];

    float rb[3][24];
#pragma unroll
    for (int dr = 0; dr < 3; ++dr) {
        const int grr = gr + dr - 1;
        const bool ok = (grr >= 0) && (grr < HH);
        const float4* rp = (const float4*)(xp + (size_t)(ok ? grr : 0) * WW);
        float4 z = make_float4(0.f, 0.f, 0.f, 0.f);
        float4 t0 = (ok && c16 > 0)        ? rp[(c16 >> 2) - 1] : z;
        float4 t1 = ok ? rp[(c16 >> 2) + 0] : z;
        float4 t2 = ok ? rp[(c16 >> 2) + 1] : z;
        float4 t3 = ok ? rp[(c16 >> 2) + 2] : z;
        float4 t4 = ok ? rp[(c16 >> 2) + 3] : z;
        float4 t5 = (ok && c16 + 16 < WW)  ? rp[(c16 >> 2) + 4] : z;
        *(float4*)&rb[dr][0]  = t0;
        *(float4*)&rb[dr][4]  = t1;
        *(float4*)&rb[dr][8]  = t2;
        *(float4*)&rb[dr][12] = t3;
        *(float4*)&rb[dr][16] = t4;
        *(float4*)&rb[dr][20] = t5;
    }

    float out[16];
#pragma unroll
    for (int p = 0; p < 16; ++p) out[p] = bs;
#pragma unroll
    for (int dr = 0; dr < 3; ++dr) {
#pragma unroll
        for (int p = 0; p < 16; ++p) {
            out[p] = fmaf(wv[dr * 3 + 0], rb[dr][3 + p], out[p]);
            out[p] = fmaf(wv[dr * 3 + 1], rb[dr][4 + p], out[p]);
            out[p] = fmaf(wv[dr * 3 + 2], rb[dr][5 + p], out[p]);
        }
    }

    float* yp = y + ((size_t)b * CDIM + c) * HW + (size_t)gr * WW + c16;
#pragma unroll
    for (int q = 0; q < 4; ++q)
        ((float4*)yp)[q] = make_float4(out[4*q], out[4*q+1], out[4*q+2], out[4*q+3]);

    if (sumsq != nullptr) {
        float ss = 0.f;
#pragma unroll
        for (int p = 0; p < 16; ++p) ss = fmaf(out[p], out[p], ss);
        for (int msk = 32; msk; msk >>= 1) ss += __shfl_xor(ss, msk);
        __shared__ float sh[4];
        if ((tid & 63) == 0) sh[tid >> 6] = ss;
        __syncthreads();
        if (tid == 0) atomicAdd(&sumsq[b * CDIM + c], sh[0] + sh[1] + sh[2] + sh[3]);
    }
}

// ---------------------------------------------------------------------------
// attn partial: per (b,h) 48x48 Gram matrix of q,k over a 256-px slice.
__global__ __launch_bounds__(256) void attn_kernel(
    const float* __restrict__ q, const float* __restrict__ k, float* __restrict__ attn)
{
    const int bh = blockIdx.y;
    const int b = bh >> 2, h = bh & 3;
    const int n0 = blockIdx.x * (HW / NSL);           // 256-wide slice
    __shared__ float qs[48][65];
    __shared__ float ks[48][65];
    const int tid = threadIdx.x;
    const int c0 = (tid >> 4) * 3, d0 = (tid & 15) * 3;
    float s[3][3] = {{0.f,0.f,0.f},{0.f,0.f,0.f},{0.f,0.f,0.f}};
    const size_t qbase = ((size_t)b * CDIM + h * CHD) * HW;
    for (int ch = 0; ch < HW / NSL; ch += 64) {
        __syncthreads();
        for (int idx = tid; idx < 48 * 64; idx += 256) {
            int r = idx >> 6, col = idx & 63;
            qs[r][col] = q[qbase + (size_t)r * HW + n0 + ch + col];
            ks[r][col] = k[qbase + (size_t)r * HW + n0 + ch + col];
        }
        __syncthreads();
        for (int n = 0; n < 64; ++n) {
            float qv[3], kv[3];
#pragma unroll
            for (int t = 0; t < 3; ++t) { qv[t] = qs[c0 + t][n]; kv[t] = ks[d0 + t][n]; }
#pragma unroll
            for (int a = 0; a < 3; ++a)
#pragma unroll
                for (int e = 0; e < 3; ++e) s[a][e] = fmaf(qv[a], kv[e], s[a][e]);
        }
    }
    float* ap = attn + (size_t)bh * 48 * 48;
#pragma unroll
    for (int a = 0; a < 3; ++a)
#pragma unroll
        for (int e = 0; e < 3; ++e) atomicAdd(&ap[(c0 + a) * 48 + (d0 + e)], s[a][e]);
}

// ---------------------------------------------------------------------------
// Build P_eff = sum_i a_i * softmax(topk_mask_i(attn_scaled)).
__global__ __launch_bounds__(64) void peff_kernel(
    const float* __restrict__ attn, const float* __restrict__ rq2, const float* __restrict__ rk2,
    const float* __restrict__ temp,
    const float* __restrict__ a1, const float* __restrict__ a2,
    const float* __restrict__ a3, const float* __restrict__ a4,
    float* __restrict__ peff)
{
    __shared__ float a_sh[48][64];
    __shared__ float e_sh[48][64];
    __shared__ float c_sh[48][64];
    const int t = threadIdx.x;
    const int r = blockIdx.x * 64 + t;                // 0..1535 (bh*48 + c)
    const int bh = r / 48, c = r - bh * 48;
    const int b = bh >> 2, h = bh & 3;
    const float T = temp[0];
    const float nq = sqrtf(rq2[b * CDIM + h * CHD + c]);
    const float scq = 1.f / fmaxf(nq, 1e-12f);
    float m = -1e30f;
    for (int d = 0; d < 48; ++d) {
        float nk = sqrtf(rk2[b * CDIM + h * CHD + d]);
        float a = attn[(size_t)r * 48 + d] * scq * (1.f / fmaxf(nk, 1e-12f)) * T;
        a_sh[d][t] = a;
        m = fmaxf(m, a);
    }
    float S1 = 0.f, S2 = 0.f, S3 = 0.f, S4 = 0.f;
    for (int d = 0; d < 48; ++d) {
        float ad = a_sh[d][t];
        int cnt = 0;
        for (int e = 0; e < 48; ++e) cnt += (a_sh[e][t] > ad) ? 1 : 0;
        float ed = expf(ad - m);
        e_sh[d][t] = ed;
        c_sh[d][t] = (float)cnt;
        if (cnt < 24) S1 += ed;
        if (cnt < 32) S2 += ed;
        if (cnt < 36) S3 += ed;
        if (cnt < 38) S4 += ed;
    }
    float w1 = a1[0] / S1, w2 = a2[0] / S2, w3 = a3[0] / S3, w4 = a4[0] / S4;
    for (int d = 0; d < 48; ++d) {
        float ed = e_sh[d][t];
        int cnt = (int)c_sh[d][t];
        float pw = 0.f;
        if (cnt < 24) pw += w1;
        if (cnt < 32) pw += w2;
        if (cnt < 36) pw += w3;
        if (cnt < 38) pw += w4;
        peff[(size_t)r * 48 + d] = ed * pw;
    }
}

// ---------------------------------------------------------------------------
// M[b] = proj_w @ blockdiag(P_eff[b,h]) : grid (B, HEADS), 192 threads.
__global__ __launch_bounds__(192) void mmat_kernel(
    const float* __restrict__ peff, const float* __restrict__ pw, float* __restrict__ M)
{
    const int b = blockIdx.x, h = blockIdx.y, o = threadIdx.x;
    __shared__ float pf[48 * 48];
    for (int i = o; i < 48 * 48; i += 192) pf[i] = peff[(size_t)(b * HEADS + h) * 2304 + i];
    __syncthreads();
    float pwr[48];
#pragma unroll
    for (int cc = 0; cc < 48; ++cc) pwr[cc] = pw[o * CDIM + h * CHD + cc];
    float* Mo = M + ((size_t)b * CDIM + o) * CDIM + h * CHD;
    for (int d = 0; d < 48; ++d) {
        float s = 0.f;
#pragma unroll
        for (int cc = 0; cc < 48; ++cc) s = fmaf(pwr[cc], pf[cc * 48 + d], s);
        Mo[d] = s;
    }
}

// ---------------------------------------------------------------------------
// SK gate: pooled mean -> relu(W1 @ .) -> W2 @ . -> softmax over HEIGHT=2
__global__ __launch_bounds__(192) void gate_kernel(
    const float* __restrict__ sum_f1, const float* __restrict__ sum_td,
    const float* __restrict__ w1, const float* __restrict__ w2, float* __restrict__ gates)
{
    const int b = blockIdx.x;
    const int t = threadIdx.x;                        // 0..191
    __shared__ float pooled[192];
    __shared__ float z[24];
    pooled[t] = (sum_f1[b * CDIM + t] + sum_td[b * CDIM + t]) * (1.f / HW);
    __syncthreads();
    if (t < 24) {
        float s = 0.f;
        for (int c2 = 0; c2 < CDIM; ++c2) s += w1[t * CDIM + c2] * pooled[c2];
        z[t] = fmaxf(s, 0.f);
    }
    __syncthreads();
    float g0 = 0.f, g1 = 0.f;
    for (int j = 0; j < 24; ++j) {
        g0 += w2[t * 24 + j] * z[j];
        g1 += w2[(CDIM + t) * 24 + j] * z[j];
    }
    float mm = fmaxf(g0, g1);
    float e0 = expf(g0 - mm), e1 = expf(g1 - mm);
    float inv = 1.f / (e0 + e1);
    gates[b * CDIM + t] = e0 * inv;
    gates[BATCH * CDIM + b * CDIM + t] = e1 * inv;
}

// ---------------------------------------------------------------------------
// Final gating combine: out = f1*g0 + td*g1 (per-(b,c) gates), float4
__global__ __launch_bounds__(256) void final_kernel(
    const float* __restrict__ f1, const float* __restrict__ td,
    const float* __restrict__ gates, float* __restrict__ out)
{
    size_t i4 = (size_t)blockIdx.x * 256 + threadIdx.x;   // float4 index
    size_t i = i4 * 4;
    int plane = (int)(i / HW);                            // b*CDIM + c
    float g0 = gates[plane], g1 = gates[BATCH * CDIM + plane];
    float4 a = ((const float4*)f1)[i4];
    float4 d = ((const float4*)td)[i4];
    float4 r;
    r.x = a.x * g0 + d.x * g1;
    r.y = a.y * g0 + d.y * g1;
    r.z = a.z * g0 + d.z * g1;
    r.w = a.w * g0 + d.w * g1;
    ((float4*)out)[i4] = r;
}

// ---------------------------------------------------------------------------
extern "C" void kernel_launch(void* const* d_in, const int* in_sizes, int n_in,
                              void* d_out, int out_size, void* d_ws, size_t ws_size,
                              hipStream_t stream)
{
    const float* T_E  = (const float*)d_in[0];
    const float* C_E  = (const float*)d_in[1];
    const float* T_D  = (const float*)d_in[2];
    const float* tn_w = (const float*)d_in[3];
    const float* tn_b = (const float*)d_in[4];
    const float* cn_w = (const float*)d_in[5];
    const float* cn_b = (const float*)d_in[6];
    const float* q_w  = (const float*)d_in[7];
    const float* q_b  = (const float*)d_in[8];
    const float* q_dw = (const float*)d_in[9];
    const float* q_db = (const float*)d_in[10];
    const float* k_w  = (const float*)d_in[11];
    const float* k_b  = (const float*)d_in[12];
    const float* k_dw = (const float*)d_in[13];
    const float* k_db = (const float*)d_in[14];
    const float* v_w  = (const float*)d_in[15];
    const float* v_b  = (const float*)d_in[16];
    const float* v_dw = (const float*)d_in[17];
    const float* v_db = (const float*)d_in[18];
    const float* temp = (const float*)d_in[19];
    const float* p_w  = (const float*)d_in[20];
    const float* p_b  = (const float*)d_in[21];
    const float* a1   = (const float*)d_in[22];
    const float* a2   = (const float*)d_in[23];
    const float* a3   = (const float*)d_in[24];
    const float* a4   = (const float*)d_in[25];
    const float* skw1 = (const float*)d_in[26];
    const float* skw2 = (const float*)d_in[27];

    float* ws = (float*)d_ws;
    // small region (atomic targets first -> covered by one memset)
    float* rq2    = ws;                    // 1536 (atomic)
    float* rk2    = rq2 + 1536;            // 1536 (atomic)
    float* sum_td = rk2 + 1536;            // 1536 (direct store)
    float* sum_f1 = sum_td + 1536;         // 1536 (direct store)
    float* attn   = sum_f1 + 1536;         // 73728 (atomic) -> memset ends at 79872
    float* peff   = attn + 73728;          // 73728
    float* gates  = peff + 73728;          // 3072
    float* Mmat   = gates + 3072;          // 294912
    float* muT    = Mmat + 294912;         // 131072
    float* rsT    = muT + 131072;
    float* muC    = rsT + 131072;
    float* rsC    = muC + 131072;          // ends < 1M floats

    const size_t BIG = (size_t)BATCH * CDIM * HW;     // 25165824 floats
    float* bufA = ws + (1 << 20);
    float* bufB = bufA + BIG;
    float* bufC = bufB + BIG;
    // ln partial sums live in bufC's region (bufC first written by conv-v later)
    float* lps  = bufC;                    // 524288
    float* lps2 = bufC + 524288;           // 524288
    float* outF = (float*)d_out;           // reused as q-buffer mid-pipeline

    // zero the atomic targets
    hipMemsetAsync(ws, 0, (size_t)79872 * sizeof(float), stream);

    // LayerNorm stats (two-pass) + T_D pooled sums
    dim3 lgrid(512, 4);
    ln_part_kernel<<<lgrid, 256, 0, stream>>>(T_E, lps, lps2);
    ln_fin_kernel<<<512, 256, 0, stream>>>(lps, lps2, muT, rsT);
    ln_part_kernel<<<lgrid, 256, 0, stream>>>(C_E, lps, lps2);
    ln_fin_kernel<<<512, 256, 0, stream>>>(lps, lps2, muC, rsC);
    rowsum_kernel<<<BATCH * CDIM, 256, 0, stream>>>(T_D, sum_td);

    // 1x1 convs with LN folded (bf16 MFMA)
    dim3 ggrid(HW / 64, BATCH);
    conv1x1_mfma_ln<<<ggrid, 256, 0, stream>>>(T_E, muT, rsT, tn_w, tn_b, q_w, q_b, bufA);
    conv1x1_mfma_ln<<<ggrid, 256, 0, stream>>>(C_E, muC, rsC, cn_w, cn_b, k_w, k_b, bufB);
    conv1x1_mfma_ln<<<ggrid, 256, 0, stream>>>(C_E, muC, rsC, cn_w, cn_b, v_w, v_b, bufC);

    // depthwise 3x3 (+ sumsq for q,k)
    dim3 dgrid(HH / 32, CDIM, BATCH);
    dwconv_kernel<<<dgrid, 256, 0, stream>>>(bufA, q_dw, q_db, outF, rq2);     // q -> d_out
    dwconv_kernel<<<dgrid, 256, 0, stream>>>(bufB, k_dw, k_db, bufA, rk2);     // k -> bufA
    dwconv_kernel<<<dgrid, 256, 0, stream>>>(bufC, v_dw, v_db, bufB, nullptr); // v -> bufB

    // attention Gram matrix + P_eff + fused proj matrix
    attn_kernel<<<dim3(NSL, BATCH * HEADS), 256, 0, stream>>>(outF, bufA, attn);
    peff_kernel<<<24, 64, 0, stream>>>(attn, rq2, rk2, temp, a1, a2, a3, a4, peff);
    mmat_kernel<<<dim3(BATCH, HEADS), 192, 0, stream>>>(peff, p_w, Mmat);

    // fusion1 = M @ v + p_b + C_E -> bufC (bf16 MFMA), then rowsum
    projfuse_mfma<<<ggrid, 256, 0, stream>>>(bufB, Mmat, p_b, C_E, bufC);
    rowsum_kernel<<<BATCH * CDIM, 256, 0, stream>>>(bufC, sum_f1);

    // SK gate + final combine
    gate_kernel<<<BATCH, 192, 0, stream>>>(sum_f1, sum_td, skw1, skw2, gates);
    final_kernel<<<(BIG / 4) / 256, 256, 0, stream>>>(bufC, T_D, gates, outF);
}

// Round 10
// 1059.455 us; speedup vs baseline: 3.1208x; 1.0988x over previous
//
#include <hip/hip_runtime.h>
#include <hip/hip_bf16.h>

// Problem constants
#define BATCH 8
#define CDIM 192
#define HH 128
#define WW 128
#define HW (HH*WW)          // 16384
#define HEADS 4
#define CHD 48
#define NSL 64              // n-slices for attn kernel (256 px each)
#define LDK 40              // padded LDS k-stride (bf16 units)

typedef __attribute__((ext_vector_type(8))) short bf16x8;
typedef __attribute__((ext_vector_type(4))) float f32x4;

__device__ inline unsigned short f2bf(float f) {
    union { float f; unsigned int u; } v; v.f = f;
    unsigned int u = v.u;
    unsigned int r = u + 0x7fff + ((u >> 16) & 1);   // RNE
    return (unsigned short)(r >> 16);
}

// ---------------------------------------------------------------------------
// One-time fp32 -> bf16 weight conversion (q/k/v 1x1 weights)
__global__ __launch_bounds__(256) void wcvt_kernel(
    const float* __restrict__ qw, const float* __restrict__ kw, const float* __restrict__ vw,
    unsigned short* __restrict__ qb, unsigned short* __restrict__ kb, unsigned short* __restrict__ vb)
{
    const int i = blockIdx.x * 256 + threadIdx.x;     // 0..36863
    if (i < CDIM * CDIM) {
        qb[i] = f2bf(qw[i]);
        kb[i] = f2bf(kw[i]);
        vb[i] = f2bf(vw[i]);
    }
}

// ---------------------------------------------------------------------------
// LayerNorm2d stats, pass 1: partial sums over a 48-channel slice.
__global__ __launch_bounds__(256) void ln_part_kernel(
    const float* __restrict__ x, float* __restrict__ ps, float* __restrict__ ps2)
{
    const int idx = blockIdx.x * 256 + threadIdx.x;   // 0 .. B*HW-1
    const int slice = blockIdx.y;                      // 0..3
    const int b = idx >> 14;
    const int p = idx & (HW - 1);
    const float* xp = x + (size_t)b * CDIM * HW + (size_t)slice * 48 * HW + p;
    float s = 0.f, s2 = 0.f;
#pragma unroll 8
    for (int c = 0; c < 48; ++c) {
        float v = xp[(size_t)c * HW];
        s += v;
        s2 = fmaf(v, v, s2);
    }
    ps [slice * (BATCH * HW) + idx] = s;
    ps2[slice * (BATCH * HW) + idx] = s2;
}

// pass 2: combine 4 partials -> mu, rstd
__global__ __launch_bounds__(256) void ln_fin_kernel(
    const float* __restrict__ ps, const float* __restrict__ ps2,
    float* __restrict__ mu, float* __restrict__ rstd)
{
    const int idx = blockIdx.x * 256 + threadIdx.x;
    const int N = BATCH * HW;
    float s  = ps [idx] + ps [N + idx] + ps [2 * N + idx] + ps [3 * N + idx];
    float s2 = ps2[idx] + ps2[N + idx] + ps2[2 * N + idx] + ps2[3 * N + idx];
    float m = s * (1.f / CDIM);
    mu[idx] = m;
    rstd[idx] = rsqrtf(s2 * (1.f / CDIM) - m * m + 1e-6f);
}

// ---------------------------------------------------------------------------
// Row sum over HW for one (b,c) plane (SK pooling), float4
__global__ __launch_bounds__(256) void rowsum_kernel(
    const float* __restrict__ x, float* __restrict__ out)
{
    const int row = blockIdx.x;                        // b*CDIM + c
    const float4* xp = (const float4*)(x + (size_t)row * HW);
    float s = 0.f;
#pragma unroll
    for (int k = 0; k < 16; ++k) {
        float4 v = xp[threadIdx.x + k * 256];
        s += (v.x + v.y) + (v.z + v.w);
    }
    for (int msk = 32; msk; msk >>= 1) s += __shfl_xor(s, msk);
    __shared__ float sh[4];
    if ((threadIdx.x & 63) == 0) sh[threadIdx.x >> 6] = s;
    __syncthreads();
    if (threadIdx.x == 0) out[row] = sh[0] + sh[1] + sh[2] + sh[3];
}

// ---------------------------------------------------------------------------
// MFMA 1x1 conv with LN folded, v2: A (bf16 weights) in REGISTERS (loaded once),
// only B (activations) staged in LDS per k-step.
// grid (HW/64, B) x 256 thr; wave w owns rows w*48..w*48+47, all 64 px.
__global__ __launch_bounds__(256) void conv1x1_mfma_ln(
    const float* __restrict__ x, const float* __restrict__ mu, const float* __restrict__ rstd,
    const float* __restrict__ lnw, const float* __restrict__ lnb,
    const unsigned short* __restrict__ wbf, const float* __restrict__ wb,
    float* __restrict__ y)
{
    __shared__ short B_s[64 * LDK];
    const int tid = threadIdx.x;
    const int p0 = blockIdx.x * 64;
    const int b  = blockIdx.y;
    const int lane = tid & 63;
    const int wid = tid >> 6;            // wave id: m-block owner AND staging k-group
    const int p_l = tid & 63;            // staging pixel
    const int m0 = wid * 48;

    // A-fragments: 3 m-frags x 6 k-steps, loaded once from bf16 weights
    bf16x8 afr[3][6];
#pragma unroll
    for (int mi = 0; mi < 3; ++mi)
#pragma unroll
        for (int ks = 0; ks < 6; ++ks) {
            const int row = m0 + mi * 16 + (lane & 15);
            const int k   = ks * 32 + (lane >> 4) * 8;
            afr[mi][ks] = *(const bf16x8*)&wbf[row * CDIM + k];
        }

    const int sidx = (b << 14) + p0 + p_l;
    const float m_ln = mu[sidx], r_ln = rstd[sidx];

    f32x4 acc[3][4];
#pragma unroll
    for (int mi = 0; mi < 3; ++mi)
#pragma unroll
        for (int nf = 0; nf < 4; ++nf) acc[mi][nf] = f32x4{0.f, 0.f, 0.f, 0.f};

    const size_t xb = (size_t)b * CDIM * HW + p0;

    for (int ks = 0; ks < 6; ++ks) {
        const int k0 = ks * 32;
        if (ks) __syncthreads();
        // stage B: 64 px x 32 k of LN(x) -> bf16
#pragma unroll
        for (int i = 0; i < 2; ++i) {
            const int c = k0 + wid * 8 + i * 4;
            float v0 = x[xb + (size_t)(c + 0) * HW + p_l];
            float v1 = x[xb + (size_t)(c + 1) * HW + p_l];
            float v2 = x[xb + (size_t)(c + 2) * HW + p_l];
            float v3 = x[xb + (size_t)(c + 3) * HW + p_l];
            v0 = (v0 - m_ln) * r_ln * lnw[c + 0] + lnb[c + 0];
            v1 = (v1 - m_ln) * r_ln * lnw[c + 1] + lnb[c + 1];
            v2 = (v2 - m_ln) * r_ln * lnw[c + 2] + lnb[c + 2];
            v3 = (v3 - m_ln) * r_ln * lnw[c + 3] + lnb[c + 3];
            unsigned int lo = f2bf(v0) | ((unsigned int)f2bf(v1) << 16);
            unsigned int hi = f2bf(v2) | ((unsigned int)f2bf(v3) << 16);
            *(uint2*)&B_s[p_l * LDK + wid * 8 + i * 4] = make_uint2(lo, hi);
        }
        __syncthreads();
        bf16x8 bfr[4];
#pragma unroll
        for (int nf = 0; nf < 4; ++nf)
            bfr[nf] = *(const bf16x8*)&B_s[(nf * 16 + (lane & 15)) * LDK + (lane >> 4) * 8];
#pragma unroll
        for (int mi = 0; mi < 3; ++mi)
#pragma unroll
            for (int nf = 0; nf < 4; ++nf)
                acc[mi][nf] = __builtin_amdgcn_mfma_f32_16x16x32_bf16(afr[mi][ks], bfr[nf], acc[mi][nf], 0, 0, 0);
    }
#pragma unroll
    for (int mi = 0; mi < 3; ++mi)
#pragma unroll
        for (int nf = 0; nf < 4; ++nf) {
            const int col = p0 + nf * 16 + (lane & 15);
#pragma unroll
            for (int r = 0; r < 4; ++r) {
                const int row = m0 + mi * 16 + (lane >> 4) * 4 + r;
                y[((size_t)b * CDIM + row) * HW + col] = acc[mi][nf][r] + wb[row];
            }
        }
}

// ---------------------------------------------------------------------------
// MFMA fused proj v2: Y = Mb16[b] @ V + pb + C_E.  A in registers, B staged.
__global__ __launch_bounds__(256) void projfuse_mfma(
    const float* __restrict__ v, const unsigned short* __restrict__ Mb,
    const float* __restrict__ pb, const float* __restrict__ resid,
    float* __restrict__ y)
{
    __shared__ short B_s[64 * LDK];
    const int tid = threadIdx.x;
    const int p0 = blockIdx.x * 64;
    const int b  = blockIdx.y;
    const int lane = tid & 63;
    const int wid = tid >> 6;
    const int p_l = tid & 63;
    const int m0 = wid * 48;

    const unsigned short* Mw = Mb + (size_t)b * CDIM * CDIM;
    bf16x8 afr[3][6];
#pragma unroll
    for (int mi = 0; mi < 3; ++mi)
#pragma unroll
        for (int ks = 0; ks < 6; ++ks) {
            const int row = m0 + mi * 16 + (lane & 15);
            const int k   = ks * 32 + (lane >> 4) * 8;
            afr[mi][ks] = *(const bf16x8*)&Mw[row * CDIM + k];
        }

    f32x4 acc[3][4];
#pragma unroll
    for (int mi = 0; mi < 3; ++mi)
#pragma unroll
        for (int nf = 0; nf < 4; ++nf) acc[mi][nf] = f32x4{0.f, 0.f, 0.f, 0.f};

    const size_t xb = (size_t)b * CDIM * HW + p0;

    for (int ks = 0; ks < 6; ++ks) {
        const int k0 = ks * 32;
        if (ks) __syncthreads();
#pragma unroll
        for (int i = 0; i < 2; ++i) {
            const int c = k0 + wid * 8 + i * 4;
            float v0 = v[xb + (size_t)(c + 0) * HW + p_l];
            float v1 = v[xb + (size_t)(c + 1) * HW + p_l];
            float v2 = v[xb + (size_t)(c + 2) * HW + p_l];
            float v3 = v[xb + (size_t)(c + 3) * HW + p_l];
            unsigned int lo = f2bf(v0) | ((unsigned int)f2bf(v1) << 16);
            unsigned int hi = f2bf(v2) | ((unsigned int)f2bf(v3) << 16);
            *(uint2*)&B_s[p_l * LDK + wid * 8 + i * 4] = make_uint2(lo, hi);
        }
        __syncthreads();
        bf16x8 bfr[4];
#pragma unroll
        for (int nf = 0; nf < 4; ++nf)
            bfr[nf] = *(const bf16x8*)&B_s[(nf * 16 + (lane & 15)) * LDK + (lane >> 4) * 8];
#pragma unroll
        for (int mi = 0; mi < 3; ++mi)
#pragma unroll
            for (int nf = 0; nf < 4; ++nf)
                acc[mi][nf] = __builtin_amdgcn_mfma_f32_16x16x32_bf16(afr[mi][ks], bfr[nf], acc[mi][nf], 0, 0, 0);
    }
#pragma unroll
    for (int mi = 0; mi < 3; ++mi)
#pragma unroll
        for (int nf = 0; nf < 4; ++nf) {
            const int col = p0 + nf * 16 + (lane & 15);
#pragma unroll
            for (int r = 0; r < 4; ++r) {
                const int row = m0 + mi * 16 + (lane >> 4) * 4 + r;
                const size_t o = ((size_t)b * CDIM + row) * HW + col;
                y[o] = acc[mi][nf][r] + pb[row] + resid[o];
            }
        }
}

// ---------------------------------------------------------------------------
// Depthwise 3x3, SAME.  Thread = 16 contiguous px in one row.
__global__ __launch_bounds__(256) void dwconv_kernel(
    const float* __restrict__ x, const float* __restrict__ w, const float* __restrict__ bias,
    float* __restrict__ y, float* __restrict__ sumsq)
{
    const int rt = blockIdx.x, c = blockIdx.y, b = blockIdx.z;
    const int tid = threadIdx.x;
    const int lrow = tid >> 3;                 // 0..31
    const int c16  = (tid & 7) * 16;           // 0,16,..,112
    const int gr = rt * 32 + lrow;             // global row
    const float* xp = x + ((size_t)b * CDIM + c) * HW;

    float wv[9];
#pragma unroll
    for (int t = 0; t < 9; ++t) wv[t] = w[c * 9 + t];
    const float bs = bias[c];

    float rb[3][24];
#pragma unroll
    for (int dr = 0; dr < 3; ++dr) {
        const int grr = gr + dr - 1;
        const bool ok = (grr >= 0) && (grr < HH);
        const float4* rp = (const float4*)(xp + (size_t)(ok ? grr : 0) * WW);
        float4 z = make_float4(0.f, 0.f, 0.f, 0.f);
        float4 t0 = (ok && c16 > 0)        ? rp[(c16 >> 2) - 1] : z;
        float4 t1 = ok ? rp[(c16 >> 2) + 0] : z;
        float4 t2 = ok ? rp[(c16 >> 2) + 1] : z;
        float4 t3 = ok ? rp[(c16 >> 2) + 2] : z;
        float4 t4 = ok ? rp[(c16 >> 2) + 3] : z;
        float4 t5 = (ok && c16 + 16 < WW)  ? rp[(c16 >> 2) + 4] : z;
        *(float4*)&rb[dr][0]  = t0;
        *(float4*)&rb[dr][4]  = t1;
        *(float4*)&rb[dr][8]  = t2;
        *(float4*)&rb[dr][12] = t3;
        *(float4*)&rb[dr][16] = t4;
        *(float4*)&rb[dr][20] = t5;
    }

    float out[16];
#pragma unroll
    for (int p = 0; p < 16; ++p) out[p] = bs;
#pragma unroll
    for (int dr = 0; dr < 3; ++dr) {
#pragma unroll
        for (int p = 0; p < 16; ++p) {
            out[p] = fmaf(wv[dr * 3 + 0], rb[dr][3 + p], out[p]);
            out[p] = fmaf(wv[dr * 3 + 1], rb[dr][4 + p], out[p]);
            out[p] = fmaf(wv[dr * 3 + 2], rb[dr][5 + p], out[p]);
        }
    }

    float* yp = y + ((size_t)b * CDIM + c) * HW + (size_t)gr * WW + c16;
#pragma unroll
    for (int q = 0; q < 4; ++q)
        ((float4*)yp)[q] = make_float4(out[4*q], out[4*q+1], out[4*q+2], out[4*q+3]);

    if (sumsq != nullptr) {
        float ss = 0.f;
#pragma unroll
        for (int p = 0; p < 16; ++p) ss = fmaf(out[p], out[p], ss);
        for (int msk = 32; msk; msk >>= 1) ss += __shfl_xor(ss, msk);
        __shared__ float sh[4];
        if ((tid & 63) == 0) sh[tid >> 6] = ss;
        __syncthreads();
        if (tid == 0) atomicAdd(&sumsq[b * CDIM + c], sh[0] + sh[1] + sh[2] + sh[3]);
    }
}

// ---------------------------------------------------------------------------
// attn partial: per (b,h) 48x48 Gram matrix of q,k over a 256-px slice.
__global__ __launch_bounds__(256) void attn_kernel(
    const float* __restrict__ q, const float* __restrict__ k, float* __restrict__ attn)
{
    const int bh = blockIdx.y;
    const int b = bh >> 2, h = bh & 3;
    const int n0 = blockIdx.x * (HW / NSL);           // 256-wide slice
    __shared__ float qs[48][65];
    __shared__ float ks[48][65];
    const int tid = threadIdx.x;
    const int c0 = (tid >> 4) * 3, d0 = (tid & 15) * 3;
    float s[3][3] = {{0.f,0.f,0.f},{0.f,0.f,0.f},{0.f,0.f,0.f}};
    const size_t qbase = ((size_t)b * CDIM + h * CHD) * HW;
    for (int ch = 0; ch < HW / NSL; ch += 64) {
        __syncthreads();
        for (int idx = tid; idx < 48 * 64; idx += 256) {
            int r = idx >> 6, col = idx & 63;
            qs[r][col] = q[qbase + (size_t)r * HW + n0 + ch + col];
            ks[r][col] = k[qbase + (size_t)r * HW + n0 + ch + col];
        }
        __syncthreads();
        for (int n = 0; n < 64; ++n) {
            float qv[3], kv[3];
#pragma unroll
            for (int t = 0; t < 3; ++t) { qv[t] = qs[c0 + t][n]; kv[t] = ks[d0 + t][n]; }
#pragma unroll
            for (int a = 0; a < 3; ++a)
#pragma unroll
                for (int e = 0; e < 3; ++e) s[a][e] = fmaf(qv[a], kv[e], s[a][e]);
        }
    }
    float* ap = attn + (size_t)bh * 48 * 48;
#pragma unroll
    for (int a = 0; a < 3; ++a)
#pragma unroll
        for (int e = 0; e < 3; ++e) atomicAdd(&ap[(c0 + a) * 48 + (d0 + e)], s[a][e]);
}

// ---------------------------------------------------------------------------
// Build P_eff = sum_i a_i * softmax(topk_mask_i(attn_scaled)).
__global__ __launch_bounds__(64) void peff_kernel(
    const float* __restrict__ attn, const float* __restrict__ rq2, const float* __restrict__ rk2,
    const float* __restrict__ temp,
    const float* __restrict__ a1, const float* __restrict__ a2,
    const float* __restrict__ a3, const float* __restrict__ a4,
    float* __restrict__ peff)
{
    __shared__ float a_sh[48][64];
    __shared__ float e_sh[48][64];
    __shared__ float c_sh[48][64];
    const int t = threadIdx.x;
    const int r = blockIdx.x * 64 + t;                // 0..1535 (bh*48 + c)
    const int bh = r / 48, c = r - bh * 48;
    const int b = bh >> 2, h = bh & 3;
    const float T = temp[0];
    const float nq = sqrtf(rq2[b * CDIM + h * CHD + c]);
    const float scq = 1.f / fmaxf(nq, 1e-12f);
    float m = -1e30f;
    for (int d = 0; d < 48; ++d) {
        float nk = sqrtf(rk2[b * CDIM + h * CHD + d]);
        float a = attn[(size_t)r * 48 + d] * scq * (1.f / fmaxf(nk, 1e-12f)) * T;
        a_sh[d][t] = a;
        m = fmaxf(m, a);
    }
    float S1 = 0.f, S2 = 0.f, S3 = 0.f, S4 = 0.f;
    for (int d = 0; d < 48; ++d) {
        float ad = a_sh[d][t];
        int cnt = 0;
        for (int e = 0; e < 48; ++e) cnt += (a_sh[e][t] > ad) ? 1 : 0;
        float ed = expf(ad - m);
        e_sh[d][t] = ed;
        c_sh[d][t] = (float)cnt;
        if (cnt < 24) S1 += ed;
        if (cnt < 32) S2 += ed;
        if (cnt < 36) S3 += ed;
        if (cnt < 38) S4 += ed;
    }
    float w1 = a1[0] / S1, w2 = a2[0] / S2, w3 = a3[0] / S3, w4 = a4[0] / S4;
    for (int d = 0; d < 48; ++d) {
        float ed = e_sh[d][t];
        int cnt = (int)c_sh[d][t];
        float pw = 0.f;
        if (cnt < 24) pw += w1;
        if (cnt < 32) pw += w2;
        if (cnt < 36) pw += w3;
        if (cnt < 38) pw += w4;
        peff[(size_t)r * 48 + d] = ed * pw;
    }
}

// ---------------------------------------------------------------------------
// M[b] = proj_w @ blockdiag(P_eff[b,h]) -> bf16 : grid (B, HEADS), 192 thr.
__global__ __launch_bounds__(192) void mmat_kernel(
    const float* __restrict__ peff, const float* __restrict__ pw, unsigned short* __restrict__ Mb)
{
    const int b = blockIdx.x, h = blockIdx.y, o = threadIdx.x;
    __shared__ float pf[48 * 48];
    for (int i = o; i < 48 * 48; i += 192) pf[i] = peff[(size_t)(b * HEADS + h) * 2304 + i];
    __syncthreads();
    float pwr[48];
#pragma unroll
    for (int cc = 0; cc < 48; ++cc) pwr[cc] = pw[o * CDIM + h * CHD + cc];
    unsigned short* Mo = Mb + ((size_t)b * CDIM + o) * CDIM + h * CHD;
    for (int d = 0; d < 48; ++d) {
        float s = 0.f;
#pragma unroll
        for (int cc = 0; cc < 48; ++cc) s = fmaf(pwr[cc], pf[cc * 48 + d], s);
        Mo[d] = f2bf(s);
    }
}

// ---------------------------------------------------------------------------
// SK gate: pooled mean -> relu(W1 @ .) -> W2 @ . -> softmax over HEIGHT=2
__global__ __launch_bounds__(192) void gate_kernel(
    const float* __restrict__ sum_f1, const float* __restrict__ sum_td,
    const float* __restrict__ w1, const float* __restrict__ w2, float* __restrict__ gates)
{
    const int b = blockIdx.x;
    const int t = threadIdx.x;                        // 0..191
    __shared__ float pooled[192];
    __shared__ float z[24];
    pooled[t] = (sum_f1[b * CDIM + t] + sum_td[b * CDIM + t]) * (1.f / HW);
    __syncthreads();
    if (t < 24) {
        float s = 0.f;
        for (int c2 = 0; c2 < CDIM; ++c2) s += w1[t * CDIM + c2] * pooled[c2];
        z[t] = fmaxf(s, 0.f);
    }
    __syncthreads();
    float g0 = 0.f, g1 = 0.f;
    for (int j = 0; j < 24; ++j) {
        g0 += w2[t * 24 + j] * z[j];
        g1 += w2[(CDIM + t) * 24 + j] * z[j];
    }
    float mm = fmaxf(g0, g1);
    float e0 = expf(g0 - mm), e1 = expf(g1 - mm);
    float inv = 1.f / (e0 + e1);
    gates[b * CDIM + t] = e0 * inv;
    gates[BATCH * CDIM + b * CDIM + t] = e1 * inv;
}

// ---------------------------------------------------------------------------
// Final gating combine: out = f1*g0 + td*g1 (per-(b,c) gates), float4
__global__ __launch_bounds__(256) void final_kernel(
    const float* __restrict__ f1, const float* __restrict__ td,
    const float* __restrict__ gates, float* __restrict__ out)
{
    size_t i4 = (size_t)blockIdx.x * 256 + threadIdx.x;   // float4 index
    size_t i = i4 * 4;
    int plane = (int)(i / HW);                            // b*CDIM + c
    float g0 = gates[plane], g1 = gates[BATCH * CDIM + plane];
    float4 a = ((const float4*)f1)[i4];
    float4 d = ((const float4*)td)[i4];
    float4 r;
    r.x = a.x * g0 + d.x * g1;
    r.y = a.y * g0 + d.y * g1;
    r.z = a.z * g0 + d.z * g1;
    r.w = a.w * g0 + d.w * g1;
    ((float4*)out)[i4] = r;
}

// ---------------------------------------------------------------------------
extern "C" void kernel_launch(void* const* d_in, const int* in_sizes, int n_in,
                              void* d_out, int out_size, void* d_ws, size_t ws_size,
                              hipStream_t stream)
{
    const float* T_E  = (const float*)d_in[0];
    const float* C_E  = (const float*)d_in[1];
    const float* T_D  = (const float*)d_in[2];
    const float* tn_w = (const float*)d_in[3];
    const float* tn_b = (const float*)d_in[4];
    const float* cn_w = (const float*)d_in[5];
    const float* cn_b = (const float*)d_in[6];
    const float* q_w  = (const float*)d_in[7];
    const float* q_b  = (const float*)d_in[8];
    const float* q_dw = (const float*)d_in[9];
    const float* q_db = (const float*)d_in[10];
    const float* k_w  = (const float*)d_in[11];
    const float* k_b  = (const float*)d_in[12];
    const float* k_dw = (const float*)d_in[13];
    const float* k_db = (const float*)d_in[14];
    const float* v_w  = (const float*)d_in[15];
    const float* v_b  = (const float*)d_in[16];
    const float* v_dw = (const float*)d_in[17];
    const float* v_db = (const float*)d_in[18];
    const float* temp = (const float*)d_in[19];
    const float* p_w  = (const float*)d_in[20];
    const float* p_b  = (const float*)d_in[21];
    const float* a1   = (const float*)d_in[22];
    const float* a2   = (const float*)d_in[23];
    const float* a3   = (const float*)d_in[24];
    const float* a4   = (const float*)d_in[25];
    const float* skw1 = (const float*)d_in[26];
    const float* skw2 = (const float*)d_in[27];

    float* ws = (float*)d_ws;
    // small region (atomic targets first -> covered by one memset)
    float* rq2    = ws;                    // 1536 (atomic)
    float* rk2    = rq2 + 1536;            // 1536 (atomic)
    float* sum_td = rk2 + 1536;            // 1536 (direct store)
    float* sum_f1 = sum_td + 1536;         // 1536 (direct store)
    float* attn   = sum_f1 + 1536;         // 73728 (atomic) -> memset ends at 79872
    float* peff   = attn + 73728;          // 73728
    float* gates  = peff + 73728;          // 3072
    float* muT    = gates + 3072;          // 131072
    float* rsT    = muT + 131072;
    float* muC    = rsT + 131072;
    float* rsC    = muC + 131072;
    unsigned short* wqb = (unsigned short*)(rsC + 131072);   // 36864 shorts
    unsigned short* wkb = wqb + CDIM * CDIM;
    unsigned short* wvb = wkb + CDIM * CDIM;
    unsigned short* Mb  = wvb + CDIM * CDIM;                 // 8*36864 shorts
    // total: 79872+73728+3072+524288+3*18432+147456 = 883712 floats < 1M

    const size_t BIG = (size_t)BATCH * CDIM * HW;     // 25165824 floats
    float* bufA = ws + (1 << 20);
    float* bufB = bufA + BIG;
    float* bufC = bufB + BIG;
    // ln partial sums live in bufC's region (bufC first written by conv-v later)
    float* lps  = bufC;                    // 524288
    float* lps2 = bufC + 524288;           // 524288
    float* outF = (float*)d_out;           // reused as q-buffer mid-pipeline

    // zero the atomic targets
    hipMemsetAsync(ws, 0, (size_t)79872 * sizeof(float), stream);

    // one-time weight bf16 conversion
    wcvt_kernel<<<(CDIM * CDIM + 255) / 256, 256, 0, stream>>>(q_w, k_w, v_w, wqb, wkb, wvb);

    // LayerNorm stats (two-pass) + T_D pooled sums
    dim3 lgrid(512, 4);
    ln_part_kernel<<<lgrid, 256, 0, stream>>>(T_E, lps, lps2);
    ln_fin_kernel<<<512, 256, 0, stream>>>(lps, lps2, muT, rsT);
    ln_part_kernel<<<lgrid, 256, 0, stream>>>(C_E, lps, lps2);
    ln_fin_kernel<<<512, 256, 0, stream>>>(lps, lps2, muC, rsC);
    rowsum_kernel<<<BATCH * CDIM, 256, 0, stream>>>(T_D, sum_td);

    // 1x1 convs with LN folded (bf16 MFMA, reg-resident A)
    dim3 ggrid(HW / 64, BATCH);
    conv1x1_mfma_ln<<<ggrid, 256, 0, stream>>>(T_E, muT, rsT, tn_w, tn_b, wqb, q_b, bufA);
    conv1x1_mfma_ln<<<ggrid, 256, 0, stream>>>(C_E, muC, rsC, cn_w, cn_b, wkb, k_b, bufB);
    conv1x1_mfma_ln<<<ggrid, 256, 0, stream>>>(C_E, muC, rsC, cn_w, cn_b, wvb, v_b, bufC);

    // depthwise 3x3 (+ sumsq for q,k)
    dim3 dgrid(HH / 32, CDIM, BATCH);
    dwconv_kernel<<<dgrid, 256, 0, stream>>>(bufA, q_dw, q_db, outF, rq2);     // q -> d_out
    dwconv_kernel<<<dgrid, 256, 0, stream>>>(bufB, k_dw, k_db, bufA, rk2);     // k -> bufA
    dwconv_kernel<<<dgrid, 256, 0, stream>>>(bufC, v_dw, v_db, bufB, nullptr); // v -> bufB

    // attention Gram matrix + P_eff + fused proj matrix (bf16)
    attn_kernel<<<dim3(NSL, BATCH * HEADS), 256, 0, stream>>>(outF, bufA, attn);
    peff_kernel<<<24, 64, 0, stream>>>(attn, rq2, rk2, temp, a1, a2, a3, a4, peff);
    mmat_kernel<<<dim3(BATCH, HEADS), 192, 0, stream>>>(peff, p_w, Mb);

    // fusion1 = M @ v + p_b + C_E -> bufC (bf16 MFMA), then rowsum
    projfuse_mfma<<<ggrid, 256, 0, stream>>>(bufB, Mb, p_b, C_E, bufC);
    rowsum_kernel<<<BATCH * CDIM, 256, 0, stream>>>(bufC, sum_f1);

    // SK gate + final combine
    gate_kernel<<<BATCH, 192, 0, stream>>>(sum_f1, sum_td, skw1, skw2, gates);
    final_kernel<<<(BIG / 4) / 256, 256, 0, stream>>>(bufC, T_D, gates, outF);
}